// Round 13
// baseline (3660.125 us; speedup 1.0000x reference)
//
#include <hip/hip_runtime.h>
#include <hip/hip_fp16.h>

// LSTM: B=256, T=1024, D=128, H=256.
// w16_kernel: W x-part -> f16 table (once).
// gx_kernel : Gx = x@Wx^T + bias, f16. Layout (uint4 units):
//             [t][bg8 32][w 8][gate 4][col 16][kqc 2], uint4 = [ctl0:rg01,rg23 | ctl1:rg01,rg23]
// rec_kernel: 32 WGs (8 batch rows) x 512 thr, 2 waves/SIMD (waves_per_eu(2,2)).
//             Wh: 48 frags/wave in regs + 16 in LDS (128 KB). LDS-pipe is the
//             measured bottleneck (R8->R11 delta ~1:1 with DS ops): per-wave DS
//             cut 432->360 cyc via NFV+2 and 8 PACKED f16 bpermutes (was 16 f32).
//             kk-outer MFMA (afr read once). gx prefetch issues into gxv directly.
// head_kernel: out[b] = sigmoid([hid, cov] @ W2^T + b2).

typedef _Float16 half8 __attribute__((ext_vector_type(8)));
typedef float f32x4 __attribute__((ext_vector_type(4)));

#define MFMA16(a, b, c) __builtin_amdgcn_mfma_f32_16x16x32_f16((a), (b), (c), 0, 0, 0)

__device__ __forceinline__ float2 h2f2(unsigned int u) {
  __half2 h;
  __builtin_memcpy(&h, &u, 4);
  return __half22float2(h);
}

// one LSTM element: returns h, updates c in place.
// Clamps only on the tanh args (exp->inf would NaN through (e-1)/(e+1));
// sigmoid paths saturate correctly unclamped: rcp(inf)=0, exp(-large)=0.
__device__ __forceinline__ float lstm_elem(float a_i, float a_f, float a_o, float a_c,
                                           float& c) {
  float eA = __expf(-a_i);
  float eC = __expf(2.f * fminf(fmaxf(a_c, -15.f), 15.f));
  float ict = (eC - 1.f) * __builtin_amdgcn_rcpf((1.f + eA) * (eC + 1.f));
  float eF = __expf(-a_f);
  float fg = __builtin_amdgcn_rcpf(1.f + eF);
  float cv = fg * c + ict;
  c = cv;
  float eO = __expf(-a_o);
  float eV = __expf(2.f * fminf(fmaxf(cv, -15.f), 15.f));
  return (eV - 1.f) * __builtin_amdgcn_rcpf((1.f + eO) * (eV + 1.f));
}

// ---------------------------------------------------------------------------
// W x-part -> f16, rows g = q*256 + r, cols 0..127.
// ---------------------------------------------------------------------------
__global__ void w16_kernel(const float* __restrict__ Wi, const float* __restrict__ Wf,
                           const float* __restrict__ Wo, const float* __restrict__ Wc,
                           __half* __restrict__ w16x)
{
  int g = blockIdx.x, c = threadIdx.x;  // 1024 blocks x 128 threads
  int q = g >> 8;
  const float* Wq = (q == 0) ? Wi : (q == 1) ? Wf : (q == 2) ? Wo : Wc;
  w16x[g * 128 + c] = __float2half_rn(Wq[(size_t)(g & 255) * 384 + c]);
}

// ---------------------------------------------------------------------------
// Phase 1: x-part GEMM, no LDS. grid=(TC/8, 16 bg16, 2), 256 thr (4 waves).
// (byte-identical to R9/R10/R11's verified producer)
// ---------------------------------------------------------------------------
__global__ __launch_bounds__(256) void gx_kernel(
    const __half* __restrict__ w16x,
    const float* __restrict__ bi, const float* __restrict__ bf,
    const float* __restrict__ bo, const float* __restrict__ bc,
    const float* __restrict__ x, unsigned* __restrict__ gx, int t0)
{
  const int tid = threadIdx.x;
  const int l = tid & 63, wv = tid >> 6;
  const int kq = l >> 4, col = l & 15;
  const int tch = blockIdx.x, bg = blockIdx.y, gh = blockIdx.z;
  const size_t brow = (size_t)(bg * 16 + col);
  const int bg8 = bg * 2 + (kq >> 1);
  const int kqc = kq & 1;

#pragma unroll
  for (int mh = 0; mh < 2; ++mh) {
    half8 afr[4][4];
#pragma unroll
    for (int mm = 0; mm < 4; ++mm) {
      int tt = t0 + tch * 8 + mh * 4 + mm;
      const float* xp = x + (brow * 1024 + tt) * 128 + kq * 8;
#pragma unroll
      for (int k = 0; k < 4; ++k) {
        float4 a = *(const float4*)(xp + k * 32);
        float4 b = *(const float4*)(xp + k * 32 + 4);
        afr[mm][k] = {(_Float16)a.x, (_Float16)a.y, (_Float16)a.z, (_Float16)a.w,
                      (_Float16)b.x, (_Float16)b.y, (_Float16)b.z, (_Float16)b.w};
      }
    }
#pragma unroll
    for (int n = 0; n < 8; ++n) {
      int gbase = gh * 512 + wv * 128 + n * 16;
      int gcol = gbase + col;
      int q = gcol >> 8;
      const float* Bq = (q == 0) ? bi : (q == 1) ? bf : (q == 2) ? bo : bc;
      float bv = Bq[gcol & 255];
      half8 wf[4];
#pragma unroll
      for (int k = 0; k < 4; ++k)
        wf[k] = *(const half8*)(w16x + (size_t)(gbase + col) * 128 + k * 32 + kq * 8);
      int gt = gbase >> 4;           // global tile 0..63
      int qg = gt >> 4;
      int wc = (gt & 15) >> 1, ctlc = gt & 1;
#pragma unroll
      for (int mm = 0; mm < 4; ++mm) {
        f32x4 acc = {bv, bv, bv, bv};
#pragma unroll
        for (int k = 0; k < 4; ++k) acc = MFMA16(afr[mm][k], wf[k], acc);
        int tl = tch * 8 + mh * 4 + mm;
        unsigned lo = (unsigned)__half_as_ushort(__float2half_rn(acc[0])) |
                      ((unsigned)__half_as_ushort(__float2half_rn(acc[1])) << 16);
        unsigned hi = (unsigned)__half_as_ushort(__float2half_rn(acc[2])) |
                      ((unsigned)__half_as_ushort(__float2half_rn(acc[3])) << 16);
        unsigned* gp = gx + (((((size_t)tl * 32 + bg8) * 8 + wc) * 4 + qg) * 16 + col) * 8 +
                       kqc * 4 + ctlc * 2;
        uint2 v = {lo, hi};
        *(uint2*)gp = v;
      }
    }
  }
}

// ---------------------------------------------------------------------------
// Phase 2: recurrence. 32 WGs x 512 thr; WG bg8 owns batch rows bg8*8..+8.
// Thread ownership: ctl_own = l>>5, kqc = (l>>4)&1, col = l&15;
//   owns rows kqc*4+rg (rg 0..3) of h-col j2 = (w*2+ctl_own)*16+col.
// Wh frag linear index i = (ctl*4+q)*8+kk; i<48 in regs, else per-wave LDS.
// ---------------------------------------------------------------------------
#define NFV 48

#define WFRAG(ctl, q, kk)                                                     \
  ((((ctl) * 4 + (q)) * 8 + (kk)) < NFV                                       \
       ? wfr[(((ctl) * 4 + (q)) * 8 + (kk))]                                  \
       : *(const half8*)(WL + ((((ctl) * 4 + (q)) * 8 + (kk)) - NFV) * 1024 + lofs))

__global__ __launch_bounds__(512) __attribute__((amdgpu_waves_per_eu(2, 2)))
void rec_kernel(
    const float* __restrict__ Wi, const float* __restrict__ Wf,
    const float* __restrict__ Wo, const float* __restrict__ Wc,
    const unsigned* __restrict__ gx, float* __restrict__ dout,
    float* __restrict__ c_plain, float* __restrict__ c_state,
    __half* __restrict__ h_state, int t0, int tc)
{
  __shared__ char lds[147456];  // 8 waves * 16 KB W frags (128K) + 16 KB h dbuf
  const int tid = threadIdx.x;
  const int l = tid & 63, w = tid >> 6;
  const int kq = l >> 4, col = l & 15;
  const int kqc = kq & 1;        // row-quad owned
  const int ctl_own = l >> 5;    // ctl half owned
  const int lofs = l * 16;
  const int bg8 = blockIdx.x;
  char* WL = lds + w * 16384;
  char* HF = lds + 131072;
  const int j2 = (w * 2 + ctl_own) * 16 + col;

  // ---- load Wh fragments: i<48 regs, else LDS (h-part cols [128,384)) ----
  half8 wfr[NFV];
#pragma unroll
  for (int ctl = 0; ctl < 2; ++ctl) {
#pragma unroll
    for (int q = 0; q < 4; ++q) {
      const float* Wq = (q == 0) ? Wi : (q == 1) ? Wf : (q == 2) ? Wo : Wc;
      int j = (w * 2 + ctl) * 16 + col;
      const float* src = Wq + (size_t)j * 384 + 128 + kq * 8;
#pragma unroll
      for (int kk = 0; kk < 8; ++kk) {
        float4 a = *(const float4*)(src + kk * 32);
        float4 b = *(const float4*)(src + kk * 32 + 4);
        half8 h = {(_Float16)a.x, (_Float16)a.y, (_Float16)a.z, (_Float16)a.w,
                   (_Float16)b.x, (_Float16)b.y, (_Float16)b.z, (_Float16)b.w};
        int i = (ctl * 4 + q) * 8 + kk;
        if (i < NFV)
          wfr[i] = h;
        else
          *(half8*)(WL + (i - NFV) * 1024 + lofs) = h;
      }
    }
  }

  // ---- h-buffer init: zero rows 8..15 of both bufs (never written again) ----
  {
    uint4 z = {0, 0, 0, 0};
    *(uint4*)(HF + (tid >> 8) * 8192 + 4096 + (tid & 255) * 16) = z;
  }
  float cst[4];
  if (t0 == 0) {
#pragma unroll
    for (int i = 0; i < 4; ++i) cst[i] = 0.f;
    uint2 z2 = {0, 0};
    *(uint2*)(HF + tid * 8) = z2;  // zero rows 0..7 of buf0 (4 KB)
  } else {
#pragma unroll
    for (int rg = 0; rg < 4; ++rg)
      cst[rg] = c_state[(size_t)bg8 * 2048 + (kqc * 4 + rg) * 256 + j2];
    int r8 = tid >> 6, c4 = tid & 63;
    uint2 v = *(const uint2*)(h_state + (size_t)bg8 * 2048 + r8 * 256 + c4 * 4);
    *(uint2*)(HF + ((t0 & 1) << 13) + r8 * 512 + ((c4 * 8) ^ ((r8 & 7) << 4))) = v;
  }
  __syncthreads();

  // gx thread base: [bg8 16K][w 2K][col 32B][kqc 16B][ctl 8B], step stride 512KB
  const char* gxb = (const char*)gx + ((size_t)bg8 * 8 + w) * 2048 +
                    col * 32 + kqc * 16 + ctl_own * 8;
  uint2 gxv[4];
#pragma unroll
  for (int q = 0; q < 4; ++q) gxv[q] = *(const uint2*)(gxb + q * 512);

  const int rswz = (l & 7) << 4;
  const int rbase = (l & 15) * 512;
  const int baddr = (l & 31) * 4;  // ds_bpermute: lane l pulls lane l&31 (R8/R10/R11-verified)

  for (int tt = 0; tt < tc; ++tt) {
    const int s = t0 + tt;
    const char* rb = HF + ((s & 1) << 13);
    char* wb = HF + (((s & 1) ^ 1) << 13);
    __syncthreads();  // prev-step h writes visible

    // ---- MFMA: kk outer, afr read ONCE; weights from regs + LDS ----
    f32x4 acc[2][4] = {{{0.f, 0.f, 0.f, 0.f}, {0.f, 0.f, 0.f, 0.f},
                        {0.f, 0.f, 0.f, 0.f}, {0.f, 0.f, 0.f, 0.f}},
                       {{0.f, 0.f, 0.f, 0.f}, {0.f, 0.f, 0.f, 0.f},
                        {0.f, 0.f, 0.f, 0.f}, {0.f, 0.f, 0.f, 0.f}}};
#pragma unroll
    for (int kk = 0; kk < 8; ++kk) {
      half8 afr = *(const half8*)(rb + rbase + ((kk * 64 + kq * 16) ^ rswz));
      acc[0][0] = MFMA16(afr, WFRAG(0, 0, kk), acc[0][0]);
      acc[0][1] = MFMA16(afr, WFRAG(0, 1, kk), acc[0][1]);
      acc[0][2] = MFMA16(afr, WFRAG(0, 2, kk), acc[0][2]);
      acc[0][3] = MFMA16(afr, WFRAG(0, 3, kk), acc[0][3]);
      acc[1][0] = MFMA16(afr, WFRAG(1, 0, kk), acc[1][0]);
      acc[1][1] = MFMA16(afr, WFRAG(1, 1, kk), acc[1][1]);
      acc[1][2] = MFMA16(afr, WFRAG(1, 2, kk), acc[1][2]);
      acc[1][3] = MFMA16(afr, WFRAG(1, 3, kk), acc[1][3]);
    }

    // ---- extract this step's gx, then issue next step's loads into gxv ----
    float g[4][4];
#pragma unroll
    for (int q = 0; q < 4; ++q) {
      float2 a = h2f2(gxv[q].x), b = h2f2(gxv[q].y);
      g[q][0] = a.x; g[q][1] = a.y; g[q][2] = b.x; g[q][3] = b.y;
    }
    {
      const char* gxn = gxb + (size_t)((tt + 1 < tc) ? tt + 1 : tt) * 524288;
#pragma unroll
      for (int q = 0; q < 4; ++q) gxv[q] = *(const uint2*)(gxn + q * 512);
    }

    // ---- redistribute ctl1 rows to lanes 32-63: 8 PACKED f16 bpermutes ----
    float P[4][4];
#pragma unroll
    for (int q = 0; q < 4; ++q) {
      auto pk01 = __builtin_amdgcn_cvt_pkrtz(acc[1][q][0], acc[1][q][1]);
      auto pk23 = __builtin_amdgcn_cvt_pkrtz(acc[1][q][2], acc[1][q][3]);
      int b01, b23;
      __builtin_memcpy(&b01, &pk01, 4);
      __builtin_memcpy(&b23, &pk23, 4);
      b01 = __builtin_amdgcn_ds_bpermute(baddr, b01);
      b23 = __builtin_amdgcn_ds_bpermute(baddr, b23);
      float2 u01 = h2f2((unsigned)b01);
      float2 u23 = h2f2((unsigned)b23);
      P[q][0] = ctl_own ? u01.x : acc[0][q][0];
      P[q][1] = ctl_own ? u01.y : acc[0][q][1];
      P[q][2] = ctl_own ? u23.x : acc[0][q][2];
      P[q][3] = ctl_own ? u23.y : acc[0][q][3];
    }

    // ---- gx add + activations: 4 useful elems on ALL 64 lanes ----
    const bool lastT = (s == 1023);
    const bool endC = (tt + 1 == tc);
#pragma unroll
    for (int rg = 0; rg < 4; ++rg) {
      float hv = lstm_elem(P[0][rg] + g[0][rg], P[1][rg] + g[1][rg],
                           P[2][rg] + g[2][rg], P[3][rg] + g[3][rg], cst[rg]);
      int row = kqc * 4 + rg;
      *(_Float16*)(wb + row * 512 + ((j2 * 2) ^ ((row & 7) << 4))) = (_Float16)hv;
      if (lastT) {
        int rrow = bg8 * 8 + row;
        dout[256 + (size_t)rrow * 256 + j2] = hv;
        c_plain[(size_t)rrow * 256 + j2] = cst[rg];
      } else if (endC) {
        h_state[(size_t)bg8 * 2048 + row * 256 + j2] = __float2half_rn(hv);
      }
    }
  }

  // ---- save c state ----
#pragma unroll
  for (int rg = 0; rg < 4; ++rg)
    c_state[(size_t)bg8 * 2048 + (kqc * 4 + rg) * 256 + j2] = cst[rg];
}

// ---------------------------------------------------------------------------
// Phase 3: out[b] = sigmoid(hid[b,:].W2[:256] + cov[b,:].W2[256:] + b2)
// ---------------------------------------------------------------------------
__global__ void head_kernel(const float* __restrict__ hid, const float* __restrict__ cpl,
                            const float* __restrict__ W2, const float* __restrict__ b2,
                            float* __restrict__ out)
{
  int b = blockIdx.x, l = threadIdx.x;  // 64 threads
  float4 hv = ((const float4*)(hid + (size_t)b * 256))[l];
  float4 wv = ((const float4*)W2)[l];
  float s = hv.x * wv.x + hv.y * wv.y + hv.z * wv.z + hv.w * wv.w;
  float4 cv = ((const float4*)(cpl + (size_t)b * 256))[l];
  float4 wc = ((const float4*)(W2 + 256))[l];
  s += cv.x * wc.x + cv.y * wc.y + cv.z * wc.z + cv.w * wc.w;
#pragma unroll
  for (int off = 32; off > 0; off >>= 1) s += __shfl_down(s, off, 64);
  if (l == 0) out[b] = 1.f / (1.f + __expf(-(s + b2[0])));
}

// ---------------------------------------------------------------------------
extern "C" void kernel_launch(void* const* d_in, const int* in_sizes, int n_in,
                              void* d_out, int out_size, void* d_ws, size_t ws_size,
                              hipStream_t stream)
{
  const float* x  = (const float*)d_in[0];
  const float* Wi = (const float*)d_in[1];
  const float* bi = (const float*)d_in[2];
  const float* Wf = (const float*)d_in[3];
  const float* bf = (const float*)d_in[4];
  const float* Wo = (const float*)d_in[5];
  const float* bo = (const float*)d_in[6];
  const float* Wc = (const float*)d_in[7];
  const float* bc = (const float*)d_in[8];
  const float* W2 = (const float*)d_in[9];
  const float* b2 = (const float*)d_in[10];
  float* out = (float*)d_out;

  // ws layout: [gx: TC*512KB][c_plain 256KB][c_state 256KB][h_state 128KB][w16x 256KB]
  char* ws = (char*)d_ws;
  const size_t state_bytes = (size_t)896 * 1024;
  size_t avail = ws_size > state_bytes ? ws_size - state_bytes : 0;
  size_t tcap = avail / 524288;
  int TC = (int)(tcap > 1024 ? 1024 : (tcap & ~(size_t)7));
  if (TC < 8) TC = 8;  // requires ws_size >= ~5.2 MB
  unsigned* gxb = (unsigned*)ws;
  float* c_plain = (float*)(ws + (size_t)TC * 524288);
  float* c_state = c_plain + 65536;
  __half* h_state = (__half*)(c_state + 65536);
  __half* w16x = (__half*)(h_state + 65536);

  w16_kernel<<<1024, 128, 0, stream>>>(Wi, Wf, Wo, Wc, w16x);
  for (int t0 = 0; t0 < 1024; t0 += TC) {
    int tcn = (1024 - t0 < TC) ? (1024 - t0) : TC;
    gx_kernel<<<dim3(tcn / 8, 16, 2), 256, 0, stream>>>(w16x, bi, bf, bo, bc, x, gxb, t0);
    rec_kernel<<<32, 512, 0, stream>>>(Wi, Wf, Wo, Wc, gxb, out, c_plain, c_state,
                                       h_state, t0, tcn);
  }
  head_kernel<<<256, 64, 0, stream>>>(out + 256, c_plain, W2, b2, out);
}

// Round 14
// 3107.618 us; speedup vs baseline: 1.1778x; 1.1778x over previous
//
#include <hip/hip_runtime.h>
#include <hip/hip_fp16.h>

// LSTM: B=256, T=1024, D=128, H=256.
// w16_kernel: W x-part -> f16 table (once).
// gx_kernel : Gx = x@Wx^T + bias, f16. Layout (uint4 units):
//             [t][bg8 32][w 8][gate 4][col 16][kqc 2], uint4 = [ctl0:rg01,rg23 | ctl1:rg01,rg23]
// rec_kernel: R11 structure EXACTLY (NFV=46: regs proven spill-free; 18 frags/wave
//             in LDS 144 KB; gnv shadow gx prefetch at step top; 16 KB h dbuf),
//             plus two reg-neutral trims: 8 PACKED f16 bpermutes (was 16 f32) and
//             clamp-trimmed activations. R13's NFV=48 spilled (WRITE_SIZE +1.5MB).
// head_kernel: out[b] = sigmoid([hid, cov] @ W2^T + b2).

typedef _Float16 half8 __attribute__((ext_vector_type(8)));
typedef float f32x4 __attribute__((ext_vector_type(4)));

#define MFMA16(a, b, c) __builtin_amdgcn_mfma_f32_16x16x32_f16((a), (b), (c), 0, 0, 0)

__device__ __forceinline__ float2 h2f2(unsigned int u) {
  __half2 h;
  __builtin_memcpy(&h, &u, 4);
  return __half22float2(h);
}

// one LSTM element: returns h, updates c in place.
// Clamps only on the tanh args (exp->inf would NaN through (e-1)/(e+1));
// sigmoid paths saturate correctly unclamped: rcp(inf)=0, exp(-large)=0.
__device__ __forceinline__ float lstm_elem(float a_i, float a_f, float a_o, float a_c,
                                           float& c) {
  float eA = __expf(-a_i);
  float eC = __expf(2.f * fminf(fmaxf(a_c, -15.f), 15.f));
  float ict = (eC - 1.f) * __builtin_amdgcn_rcpf((1.f + eA) * (eC + 1.f));
  float eF = __expf(-a_f);
  float fg = __builtin_amdgcn_rcpf(1.f + eF);
  float cv = fg * c + ict;
  c = cv;
  float eO = __expf(-a_o);
  float eV = __expf(2.f * fminf(fmaxf(cv, -15.f), 15.f));
  return (eV - 1.f) * __builtin_amdgcn_rcpf((1.f + eO) * (eV + 1.f));
}

// ---------------------------------------------------------------------------
// W x-part -> f16, rows g = q*256 + r, cols 0..127.
// ---------------------------------------------------------------------------
__global__ void w16_kernel(const float* __restrict__ Wi, const float* __restrict__ Wf,
                           const float* __restrict__ Wo, const float* __restrict__ Wc,
                           __half* __restrict__ w16x)
{
  int g = blockIdx.x, c = threadIdx.x;  // 1024 blocks x 128 threads
  int q = g >> 8;
  const float* Wq = (q == 0) ? Wi : (q == 1) ? Wf : (q == 2) ? Wo : Wc;
  w16x[g * 128 + c] = __float2half_rn(Wq[(size_t)(g & 255) * 384 + c]);
}

// ---------------------------------------------------------------------------
// Phase 1: x-part GEMM, no LDS. grid=(TC/8, 16 bg16, 2), 256 thr (4 waves).
// (byte-identical to R9-R13's verified producer)
// ---------------------------------------------------------------------------
__global__ __launch_bounds__(256) void gx_kernel(
    const __half* __restrict__ w16x,
    const float* __restrict__ bi, const float* __restrict__ bf,
    const float* __restrict__ bo, const float* __restrict__ bc,
    const float* __restrict__ x, unsigned* __restrict__ gx, int t0)
{
  const int tid = threadIdx.x;
  const int l = tid & 63, wv = tid >> 6;
  const int kq = l >> 4, col = l & 15;
  const int tch = blockIdx.x, bg = blockIdx.y, gh = blockIdx.z;
  const size_t brow = (size_t)(bg * 16 + col);
  const int bg8 = bg * 2 + (kq >> 1);
  const int kqc = kq & 1;

#pragma unroll
  for (int mh = 0; mh < 2; ++mh) {
    half8 afr[4][4];
#pragma unroll
    for (int mm = 0; mm < 4; ++mm) {
      int tt = t0 + tch * 8 + mh * 4 + mm;
      const float* xp = x + (brow * 1024 + tt) * 128 + kq * 8;
#pragma unroll
      for (int k = 0; k < 4; ++k) {
        float4 a = *(const float4*)(xp + k * 32);
        float4 b = *(const float4*)(xp + k * 32 + 4);
        afr[mm][k] = {(_Float16)a.x, (_Float16)a.y, (_Float16)a.z, (_Float16)a.w,
                      (_Float16)b.x, (_Float16)b.y, (_Float16)b.z, (_Float16)b.w};
      }
    }
#pragma unroll
    for (int n = 0; n < 8; ++n) {
      int gbase = gh * 512 + wv * 128 + n * 16;
      int gcol = gbase + col;
      int q = gcol >> 8;
      const float* Bq = (q == 0) ? bi : (q == 1) ? bf : (q == 2) ? bo : bc;
      float bv = Bq[gcol & 255];
      half8 wf[4];
#pragma unroll
      for (int k = 0; k < 4; ++k)
        wf[k] = *(const half8*)(w16x + (size_t)(gbase + col) * 128 + k * 32 + kq * 8);
      int gt = gbase >> 4;           // global tile 0..63
      int qg = gt >> 4;
      int wc = (gt & 15) >> 1, ctlc = gt & 1;
#pragma unroll
      for (int mm = 0; mm < 4; ++mm) {
        f32x4 acc = {bv, bv, bv, bv};
#pragma unroll
        for (int k = 0; k < 4; ++k) acc = MFMA16(afr[mm][k], wf[k], acc);
        int tl = tch * 8 + mh * 4 + mm;
        unsigned lo = (unsigned)__half_as_ushort(__float2half_rn(acc[0])) |
                      ((unsigned)__half_as_ushort(__float2half_rn(acc[1])) << 16);
        unsigned hi = (unsigned)__half_as_ushort(__float2half_rn(acc[2])) |
                      ((unsigned)__half_as_ushort(__float2half_rn(acc[3])) << 16);
        unsigned* gp = gx + (((((size_t)tl * 32 + bg8) * 8 + wc) * 4 + qg) * 16 + col) * 8 +
                       kqc * 4 + ctlc * 2;
        uint2 v = {lo, hi};
        *(uint2*)gp = v;
      }
    }
  }
}

// ---------------------------------------------------------------------------
// Phase 2: recurrence. 32 WGs x 512 thr; WG bg8 owns batch rows bg8*8..+8.
// Thread ownership: ctl_own = l>>5, kqc = (l>>4)&1, col = l&15;
//   owns rows kqc*4+rg (rg 0..3) of h-col j2 = (w*2+ctl_own)*16+col.
// Wh frag linear index i = (ctl*4+q)*8+kk; i<46 in regs, else per-wave LDS.
// ---------------------------------------------------------------------------
#define NFV 46

#define WFRAG(ctl, q, kk)                                                     \
  ((((ctl) * 4 + (q)) * 8 + (kk)) < NFV                                       \
       ? wfr[(((ctl) * 4 + (q)) * 8 + (kk))]                                  \
       : *(const half8*)(WL + ((((ctl) * 4 + (q)) * 8 + (kk)) - NFV) * 1024 + lofs))

__global__ __launch_bounds__(512) __attribute__((amdgpu_waves_per_eu(2, 2)))
void rec_kernel(
    const float* __restrict__ Wi, const float* __restrict__ Wf,
    const float* __restrict__ Wo, const float* __restrict__ Wc,
    const unsigned* __restrict__ gx, float* __restrict__ dout,
    float* __restrict__ c_plain, float* __restrict__ c_state,
    __half* __restrict__ h_state, int t0, int tc)
{
  __shared__ char lds[163840];  // 8 waves * 18 KB W frags (144K) + 16 KB h dbuf
  const int tid = threadIdx.x;
  const int l = tid & 63, w = tid >> 6;
  const int kq = l >> 4, col = l & 15;
  const int kqc = kq & 1;        // row-quad owned
  const int ctl_own = l >> 5;    // ctl half owned
  const int lofs = l * 16;
  const int bg8 = blockIdx.x;
  char* WL = lds + w * 18432;
  char* HF = lds + 147456;
  const int j2 = (w * 2 + ctl_own) * 16 + col;

  // ---- load Wh fragments: i<46 regs, else LDS (h-part cols [128,384)) ----
  half8 wfr[NFV];
#pragma unroll
  for (int ctl = 0; ctl < 2; ++ctl) {
#pragma unroll
    for (int q = 0; q < 4; ++q) {
      const float* Wq = (q == 0) ? Wi : (q == 1) ? Wf : (q == 2) ? Wo : Wc;
      int j = (w * 2 + ctl) * 16 + col;
      const float* src = Wq + (size_t)j * 384 + 128 + kq * 8;
#pragma unroll
      for (int kk = 0; kk < 8; ++kk) {
        float4 a = *(const float4*)(src + kk * 32);
        float4 b = *(const float4*)(src + kk * 32 + 4);
        half8 h = {(_Float16)a.x, (_Float16)a.y, (_Float16)a.z, (_Float16)a.w,
                   (_Float16)b.x, (_Float16)b.y, (_Float16)b.z, (_Float16)b.w};
        int i = (ctl * 4 + q) * 8 + kk;
        if (i < NFV)
          wfr[i] = h;
        else
          *(half8*)(WL + (i - NFV) * 1024 + lofs) = h;
      }
    }
  }

  // ---- h-buffer init: zero rows 8..15 of both bufs (never written again) ----
  {
    uint4 z = {0, 0, 0, 0};
    *(uint4*)(HF + (tid >> 8) * 8192 + 4096 + (tid & 255) * 16) = z;
  }
  float cst[4];
  if (t0 == 0) {
#pragma unroll
    for (int i = 0; i < 4; ++i) cst[i] = 0.f;
    uint2 z2 = {0, 0};
    *(uint2*)(HF + tid * 8) = z2;  // zero rows 0..7 of buf0 (4 KB)
  } else {
#pragma unroll
    for (int rg = 0; rg < 4; ++rg)
      cst[rg] = c_state[(size_t)bg8 * 2048 + (kqc * 4 + rg) * 256 + j2];
    int r8 = tid >> 6, c4 = tid & 63;
    uint2 v = *(const uint2*)(h_state + (size_t)bg8 * 2048 + r8 * 256 + c4 * 4);
    *(uint2*)(HF + ((t0 & 1) << 13) + r8 * 512 + ((c4 * 8) ^ ((r8 & 7) << 4))) = v;
  }
  __syncthreads();

  // gx thread base: [bg8 16K][w 2K][col 32B][kqc 16B][ctl 8B], step stride 512KB
  const char* gxb = (const char*)gx + ((size_t)bg8 * 8 + w) * 2048 +
                    col * 32 + kqc * 16 + ctl_own * 8;
  uint2 gxv[4];
#pragma unroll
  for (int q = 0; q < 4; ++q) gxv[q] = *(const uint2*)(gxb + q * 512);

  const int rswz = (l & 7) << 4;
  const int rbase = (l & 15) * 512;
  const int baddr = (l & 31) * 4;  // ds_bpermute: lane l pulls lane l&31 (R8/R10/R11-verified)

  for (int tt = 0; tt < tc; ++tt) {
    const int s = t0 + tt;
    const char* rb = HF + ((s & 1) << 13);
    char* wb = HF + (((s & 1) ^ 1) << 13);
    __syncthreads();  // prev-step h writes visible

    // ---- prefetch NEXT step's gx (consumed next iteration) ----
    const char* gxn = gxb + (size_t)((tt + 1 < tc) ? tt + 1 : tt) * 524288;
    uint2 gnv[4];
#pragma unroll
    for (int q = 0; q < 4; ++q) gnv[q] = *(const uint2*)(gxn + q * 512);

    // ---- MFMA: kk outer, afr read ONCE; weights from regs + LDS ----
    f32x4 acc[2][4] = {{{0.f, 0.f, 0.f, 0.f}, {0.f, 0.f, 0.f, 0.f},
                        {0.f, 0.f, 0.f, 0.f}, {0.f, 0.f, 0.f, 0.f}},
                       {{0.f, 0.f, 0.f, 0.f}, {0.f, 0.f, 0.f, 0.f},
                        {0.f, 0.f, 0.f, 0.f}, {0.f, 0.f, 0.f, 0.f}}};
#pragma unroll
    for (int kk = 0; kk < 8; ++kk) {
      half8 afr = *(const half8*)(rb + rbase + ((kk * 64 + kq * 16) ^ rswz));
      acc[0][0] = MFMA16(afr, WFRAG(0, 0, kk), acc[0][0]);
      acc[0][1] = MFMA16(afr, WFRAG(0, 1, kk), acc[0][1]);
      acc[0][2] = MFMA16(afr, WFRAG(0, 2, kk), acc[0][2]);
      acc[0][3] = MFMA16(afr, WFRAG(0, 3, kk), acc[0][3]);
      acc[1][0] = MFMA16(afr, WFRAG(1, 0, kk), acc[1][0]);
      acc[1][1] = MFMA16(afr, WFRAG(1, 1, kk), acc[1][1]);
      acc[1][2] = MFMA16(afr, WFRAG(1, 2, kk), acc[1][2]);
      acc[1][3] = MFMA16(afr, WFRAG(1, 3, kk), acc[1][3]);
    }

    // ---- redistribute ctl1 rows to lanes 32-63: 8 PACKED f16 bpermutes ----
    float P[4][4];
#pragma unroll
    for (int q = 0; q < 4; ++q) {
      auto pk01 = __builtin_amdgcn_cvt_pkrtz(acc[1][q][0], acc[1][q][1]);
      auto pk23 = __builtin_amdgcn_cvt_pkrtz(acc[1][q][2], acc[1][q][3]);
      int b01, b23;
      __builtin_memcpy(&b01, &pk01, 4);
      __builtin_memcpy(&b23, &pk23, 4);
      b01 = __builtin_amdgcn_ds_bpermute(baddr, b01);
      b23 = __builtin_amdgcn_ds_bpermute(baddr, b23);
      float2 u01 = h2f2((unsigned)b01);
      float2 u23 = h2f2((unsigned)b23);
      P[q][0] = ctl_own ? u01.x : acc[0][q][0];
      P[q][1] = ctl_own ? u01.y : acc[0][q][1];
      P[q][2] = ctl_own ? u23.x : acc[0][q][2];
      P[q][3] = ctl_own ? u23.y : acc[0][q][3];
    }

    // ---- gx add + activations: 4 useful elems on ALL 64 lanes ----
    const bool lastT = (s == 1023);
    const bool endC = (tt + 1 == tc);
    float g[4][4];
#pragma unroll
    for (int q = 0; q < 4; ++q) {
      float2 a = h2f2(gxv[q].x), b = h2f2(gxv[q].y);
      g[q][0] = a.x; g[q][1] = a.y; g[q][2] = b.x; g[q][3] = b.y;
    }
#pragma unroll
    for (int rg = 0; rg < 4; ++rg) {
      float hv = lstm_elem(P[0][rg] + g[0][rg], P[1][rg] + g[1][rg],
                           P[2][rg] + g[2][rg], P[3][rg] + g[3][rg], cst[rg]);
      int row = kqc * 4 + rg;
      *(_Float16*)(wb + row * 512 + ((j2 * 2) ^ ((row & 7) << 4))) = (_Float16)hv;
      if (lastT) {
        int rrow = bg8 * 8 + row;
        dout[256 + (size_t)rrow * 256 + j2] = hv;
        c_plain[(size_t)rrow * 256 + j2] = cst[rg];
      } else if (endC) {
        h_state[(size_t)bg8 * 2048 + row * 256 + j2] = __float2half_rn(hv);
      }
    }
#pragma unroll
    for (int q = 0; q < 4; ++q) gxv[q] = gnv[q];
  }

  // ---- save c state ----
#pragma unroll
  for (int rg = 0; rg < 4; ++rg)
    c_state[(size_t)bg8 * 2048 + (kqc * 4 + rg) * 256 + j2] = cst[rg];
}

// ---------------------------------------------------------------------------
// Phase 3: out[b] = sigmoid(hid[b,:].W2[:256] + cov[b,:].W2[256:] + b2)
// ---------------------------------------------------------------------------
__global__ void head_kernel(const float* __restrict__ hid, const float* __restrict__ cpl,
                            const float* __restrict__ W2, const float* __restrict__ b2,
                            float* __restrict__ out)
{
  int b = blockIdx.x, l = threadIdx.x;  // 64 threads
  float4 hv = ((const float4*)(hid + (size_t)b * 256))[l];
  float4 wv = ((const float4*)W2)[l];
  float s = hv.x * wv.x + hv.y * wv.y + hv.z * wv.z + hv.w * wv.w;
  float4 cv = ((const float4*)(cpl + (size_t)b * 256))[l];
  float4 wc = ((const float4*)(W2 + 256))[l];
  s += cv.x * wc.x + cv.y * wc.y + cv.z * wc.z + cv.w * wc.w;
#pragma unroll
  for (int off = 32; off > 0; off >>= 1) s += __shfl_down(s, off, 64);
  if (l == 0) out[b] = 1.f / (1.f + __expf(-(s + b2[0])));
}

// ---------------------------------------------------------------------------
extern "C" void kernel_launch(void* const* d_in, const int* in_sizes, int n_in,
                              void* d_out, int out_size, void* d_ws, size_t ws_size,
                              hipStream_t stream)
{
  const float* x  = (const float*)d_in[0];
  const float* Wi = (const float*)d_in[1];
  const float* bi = (const float*)d_in[2];
  const float* Wf = (const float*)d_in[3];
  const float* bf = (const float*)d_in[4];
  const float* Wo = (const float*)d_in[5];
  const float* bo = (const float*)d_in[6];
  const float* Wc = (const float*)d_in[7];
  const float* bc = (const float*)d_in[8];
  const float* W2 = (const float*)d_in[9];
  const float* b2 = (const float*)d_in[10];
  float* out = (float*)d_out;

  // ws layout: [gx: TC*512KB][c_plain 256KB][c_state 256KB][h_state 128KB][w16x 256KB]
  char* ws = (char*)d_ws;
  const size_t state_bytes = (size_t)896 * 1024;
  size_t avail = ws_size > state_bytes ? ws_size - state_bytes : 0;
  size_t tcap = avail / 524288;
  int TC = (int)(tcap > 1024 ? 1024 : (tcap & ~(size_t)7));
  if (TC < 8) TC = 8;  // requires ws_size >= ~5.2 MB
  unsigned* gxb = (unsigned*)ws;
  float* c_plain = (float*)(ws + (size_t)TC * 524288);
  float* c_state = c_plain + 65536;
  __half* h_state = (__half*)(c_state + 65536);
  __half* w16x = (__half*)(h_state + 65536);

  w16_kernel<<<1024, 128, 0, stream>>>(Wi, Wf, Wo, Wc, w16x);
  for (int t0 = 0; t0 < 1024; t0 += TC) {
    int tcn = (1024 - t0 < TC) ? (1024 - t0) : TC;
    gx_kernel<<<dim3(tcn / 8, 16, 2), 256, 0, stream>>>(w16x, bi, bf, bo, bc, x, gxb, t0);
    rec_kernel<<<32, 512, 0, stream>>>(Wi, Wf, Wo, Wc, gxb, out, c_plain, c_state,
                                       h_state, t0, tcn);
  }
  head_kernel<<<256, 64, 0, stream>>>(out + 256, c_plain, W2, b2, out);
}